// Round 6
// baseline (1173.713 us; speedup 1.0000x reference)
//
#include <hip/hip_runtime.h>

#define B_TOT 4096
#define T_LEN 256
#define NCH   32

typedef float f2 __attribute__((ext_vector_type(2)));
typedef float f4 __attribute__((ext_vector_type(4)));

__device__ __forceinline__ float rdlane(float v, int l) {
    return __int_as_float(__builtin_amdgcn_readlane(__float_as_int(v), l));
}
__device__ __forceinline__ float xor1f(float x) {
    return __int_as_float(__builtin_amdgcn_mov_dpp(__float_as_int(x), 0xB1, 0xF, 0xF, true));
}
__device__ __forceinline__ float xor2f(float x) {
    return __int_as_float(__builtin_amdgcn_mov_dpp(__float_as_int(x), 0x4E, 0xF, 0xF, true));
}
__device__ __forceinline__ float xor3f(float x) {
    return __int_as_float(__builtin_amdgcn_mov_dpp(__float_as_int(x), 0x1B, 0xF, 0xF, true));
}
// xor-8 within 16-lane rows: row_ror:8, since (l+8)%16 == l^8 (either ror direction)
__device__ __forceinline__ float xor8f(float x) {
    return __int_as_float(__builtin_amdgcn_mov_dpp(__float_as_int(x), 0x128, 0xF, 0xF, true));
}
__device__ __forceinline__ float xsign(float x, unsigned m) {
    return __int_as_float(__float_as_int(x) ^ (int)m);
}
__device__ __forceinline__ float fast_sig(float x) {
    return __builtin_amdgcn_rcpf(1.0f + __expf(-x));
}
__device__ __forceinline__ float fast_tanh(float x) {
    return fmaf(-2.0f, __builtin_amdgcn_rcpf(__expf(2.0f * x) + 1.0f), 1.0f);
}

// full-range sincos (Cody-Waite pi-reduction + Taylor 11/12, abs err ~1e-7)
__device__ __forceinline__ void fast_sincos(float x, float& s, float& c) {
    float k = rintf(x * 0.3183098861837907f);
    float r = fmaf(-k, 3.14159274101257324f, x);
    r = fmaf(-k, -8.74227765734758577e-8f, r);
    float r2 = r * r;
    float sp = -2.50521084e-8f;
    sp = fmaf(sp, r2, 2.75573192e-6f);
    sp = fmaf(sp, r2, -1.98412698e-4f);
    sp = fmaf(sp, r2, 8.33333333e-3f);
    sp = fmaf(sp, r2, -1.66666667e-1f);
    float sv = fmaf(sp * r2, r, r);
    float cp = 2.08767570e-9f;
    cp = fmaf(cp, r2, -2.75573192e-7f);
    cp = fmaf(cp, r2, 2.48015873e-5f);
    cp = fmaf(cp, r2, -1.38888889e-3f);
    cp = fmaf(cp, r2, 4.16666667e-2f);
    cp = fmaf(cp, r2, -0.5f);
    float cv = fmaf(cp, r2, 1.0f);
    float sgn = ((int)k & 1) ? -1.0f : 1.0f;
    s = sv * sgn;
    c = cv * sgn;
}

// ---------------- TCN: 3x (conv1d k=3 'same' + bias + ReLU) ----------------
__global__ __launch_bounds__(256) void tcn_kernel(
    const float* __restrict__ x,
    const float* __restrict__ cw1, const float* __restrict__ cb1,
    const float* __restrict__ cw2, const float* __restrict__ cb2,
    const float* __restrict__ cw3, const float* __restrict__ cb3,
    float* __restrict__ out)
{
    __shared__ float bufA[NCH * 257];
    __shared__ float bufB[NCH * 257];
    __shared__ float sW[NCH * 97];
    __shared__ float sB[NCH];

    const int b   = blockIdx.x;
    const int tid = threadIdx.x;
    const float* xb = x + (size_t)b * T_LEN * NCH;

    #pragma unroll
    for (int c = 0; c < 32; ++c) {
        int idx = c * 256 + tid;
        int t = idx >> 5, f = idx & 31;
        bufA[f * 257 + t] = xb[idx];
    }
    __syncthreads();

    float* bin  = bufA;
    float* bout = bufB;
    const int o  = tid & 31;
    const int t0 = (tid >> 5) * 32;

    for (int layer = 0; layer < 3; ++layer) {
        const float* Wg = (layer == 0) ? cw1 : ((layer == 1) ? cw2 : cw3);
        const float* Bg = (layer == 0) ? cb1 : ((layer == 1) ? cb2 : cb3);
        for (int idx = tid; idx < 32 * 96; idx += 256) {
            int oo = idx / 96, rem = idx - oo * 96;
            sW[oo * 97 + rem] = Wg[idx];
        }
        if (tid < 32) sB[tid] = Bg[tid];
        __syncthreads();

        float acc[32];
        const float bias = sB[o];
        #pragma unroll
        for (int tt = 0; tt < 32; ++tt) acc[tt] = bias;

        for (int i = 0; i < 32; ++i) {
            const float w0 = sW[o * 97 + i * 3 + 0];
            const float w1 = sW[o * 97 + i * 3 + 1];
            const float w2 = sW[o * 97 + i * 3 + 2];
            const float* row = bin + i * 257;
            float vm = (t0 == 0) ? 0.0f : row[t0 - 1];
            float v0 = row[t0];
            #pragma unroll
            for (int tt = 0; tt < 32; ++tt) {
                float vp = (t0 + tt == 255) ? 0.0f : row[t0 + tt + 1];
                acc[tt] = fmaf(w0, vm, acc[tt]);
                acc[tt] = fmaf(w1, v0, acc[tt]);
                acc[tt] = fmaf(w2, vp, acc[tt]);
                vm = v0; v0 = vp;
            }
        }
        #pragma unroll
        for (int tt = 0; tt < 32; ++tt)
            bout[o * 257 + t0 + tt] = fmaxf(acc[tt], 0.0f);
        __syncthreads();
        float* tmp = bin; bin = bout; bout = tmp;
    }

    float* og = out + (size_t)b * T_LEN * NCH;
    #pragma unroll
    for (int c = 0; c < 32; ++c) {
        int idx = c * 256 + tid;
        int t = idx >> 5, f = idx & 31;
        og[idx] = bin[f * 257 + t];
    }
}

// ---------------- recurrent scan: 1 batch row per 64-thread block ----------
// Zero LDS. Weights resident in registers (rows lane & lane+64, f2-packed);
// x_t/h broadcast via v_readlane (systolic matvec); quantum circuit fully
// in-register with deferred-CNOT masks (see round-5 derivation).
__global__ __launch_bounds__(64) void scan_kernel(
    const float* __restrict__ tcn,
    const float* __restrict__ W_ih, const float* __restrict__ W_hh,
    const float* __restrict__ b_ih, const float* __restrict__ b_hh,
    const float* __restrict__ qw,
    const float* __restrict__ Wq, const float* __restrict__ bq,
    const float* __restrict__ Wo, const float* __restrict__ bo,
    float* __restrict__ out)
{
    const int lane = threadIdx.x;
    const int b    = blockIdx.x;
    const float* xrow = tcn + (size_t)b * T_LEN * NCH;

    // ---- one-time: weights into registers, packed (row lane, row lane+64) ----
    f2 wih[32], whh[32];
    #pragma unroll
    for (int k = 0; k < 32; ++k) {
        wih[k] = f2{ W_ih[lane * 32 + k], W_ih[(lane + 64) * 32 + k] };
        whh[k] = f2{ W_hh[lane * 32 + k], W_hh[(lane + 64) * 32 + k] };
    }
    const f2 bias01 = f2{ b_ih[lane] + b_hh[lane],
                          b_ih[lane + 64] + b_hh[lane + 64] };

    // ---- one-time: variational trig (uniform scalars) ----
    float ssu[18], ccu[18];
    {
        float s0, c0;
        int j = (lane < 18) ? lane : 0;
        fast_sincos(0.5f * qw[j], s0, c0);
        #pragma unroll
        for (int i = 0; i < 18; ++i) { ssu[i] = rdlane(s0, i); ccu[i] = rdlane(c0, i); }
    }
    // per-lane layer-1 coeffs (wire = lane; valid lanes 0-5)
    float vs1 = ssu[0], vc1 = ccu[0];
    #pragma unroll
    for (int i = 1; i < 6; ++i) {
        vs1 = (lane == i) ? ssu[i] : vs1;
        vc1 = (lane == i) ? ccu[i] : vc1;
    }
    // layer-2/3 per-lane pre-signed sines (sign = parity(lane & mu))
    const int MU2[6] = {31, 48, 56, 60, 62, 63};
    const int MU3[6] = {53, 47, 23, 43, 21, 42};
    float ssl2[6], ssl3[6], cc2[6], cc3[6];
    #pragma unroll
    for (int q = 0; q < 6; ++q) {
        ssl2[q] = (__popc(lane & MU2[q]) & 1) ? ssu[6 + q]  : -ssu[6 + q];
        ssl3[q] = (__popc(lane & MU3[q]) & 1) ? ssu[12 + q] : -ssu[12 + q];
        cc2[q] = ccu[6 + q];
        cc3[q] = ccu[12 + q];
    }
    // WH butterfly sign masks
    unsigned nm[6];
    #pragma unroll
    for (int q = 0; q < 6; ++q) nm[q] = (lane & (32 >> q)) ? 0u : 0x80000000u;
    // encoding gather sources (wires lane+1, lane+2 mod 6)
    const int r1 = (lane + 1) % 6, r2 = (lane + 2) % 6;

    float wqr[6] = {0, 0, 0, 0, 0, 0};
    float bqr = 0.0f, wor = 0.0f;
    if (lane < 32) {
        #pragma unroll
        for (int k = 0; k < 6; ++k) wqr[k] = Wq[lane * 6 + k];
        bqr = bq[lane];
        wor = Wo[lane];
    }

    float hh = 0.0f, cxs = 0.0f;
    float xpre = (lane < 32) ? xrow[lane] : 0.0f;

    for (int t = 0; t < T_LEN; ++t) {
        float xnext = (lane < 32 && t < T_LEN - 1) ? xrow[(t + 1) * 32 + lane] : 0.0f;

        // ---- gates via readlane-systolic: acc.x = gates[lane], acc.y = gates[lane+64]
        f2 acc = bias01, accb = f2{0.0f, 0.0f};
        #pragma unroll
        for (int k = 0; k < 32; k += 2) {
            float xk  = rdlane(xpre, k),     hk  = rdlane(hh, k);
            float xk1 = rdlane(xpre, k + 1), hk1 = rdlane(hh, k + 1);
            acc  = __builtin_elementwise_fma(wih[k],     f2{xk,  xk},  acc);
            acc  = __builtin_elementwise_fma(whh[k],     f2{hk,  hk},  acc);
            accb = __builtin_elementwise_fma(wih[k + 1], f2{xk1, xk1}, accb);
            accb = __builtin_elementwise_fma(whh[k + 1], f2{hk1, hk1}, accb);
        }
        acc += accb;
        float acc0 = acc.x, acc1 = acc.y;

        float fg = __shfl_xor(acc0, 32, 64);
        float og = __shfl_xor(acc1, 32, 64);
        float c  = fast_sig(fg) * cxs + fast_sig(acc0) * fast_tanh(acc1);
        float h  = fast_sig(og) * fast_tanh(c);
        h = 3.99f * h * (1.0f - h);                       // logistic map
        float h0 = rdlane(h, 0), h1 = rdlane(h, 1);
        float hen0 = fmaf(-1.4f * h0, h0, 1.0f) + h1;     // henon
        float hen1 = 0.3f * h0;
        h = (lane == 0) ? hen0 : h;
        h = (lane == 1) ? hen1 : h;
        cxs = c;

        // ---- encoding columns (fused RZ*RY*RX |0>, + layer-1 RY fold) ----
        float s_own, c_own;
        fast_sincos(0.5f * h, s_own, c_own);
        float s1v = __shfl(s_own, r1, 64), c1v = __shfl(c_own, r1, 64);
        float s2v = __shfl(s_own, r2, 64), c2v = __shfl(c_own, r2, 64);
        float A_ = c1v * c_own, Bv = s1v * s_own;
        float C_ = s1v * c_own, D_ = c1v * s_own;
        float ur = fmaf(Bv, s2v,  A_ * c2v);
        float ui = fmaf(Bv, c2v, -(A_ * s2v));
        float pr = fmaf(D_, s2v,  C_ * c2v);
        float pi = fmaf(C_, s2v, -(D_ * c2v));
        float nur_ = fmaf(vc1, ur, -(vs1 * pr));
        float nui_ = fmaf(vc1, ui, -(vs1 * pi));
        float npr_ = fmaf(vs1, ur,  vc1 * pr);
        float npi_ = fmaf(vs1, ui,  vc1 * pi);

        // ---- product state via readlane distribution (no LDS) ----
        float re, im;
        {
            float u0r = rdlane(nur_, 0), u0i = rdlane(nui_, 0);
            float p0r = rdlane(npr_, 0), p0i = rdlane(npi_, 0);
            bool hi0 = (lane & 32) != 0;
            re = hi0 ? p0r : u0r;
            im = hi0 ? p0i : u0i;
        }
        #pragma unroll
        for (int i = 1; i < 6; ++i) {
            float uir = rdlane(nur_, i), uii = rdlane(nui_, i);
            float pir = rdlane(npr_, i), pii = rdlane(npi_, i);
            const bool hi = (lane & (32 >> i)) != 0;
            float gr = hi ? pir : uir;
            float gi = hi ? pii : uii;
            float nr = fmaf(re, gr, -(im * gi));
            float ni = fmaf(re, gi,   im * gr);
            re = nr; im = ni;
        }

        // ---- layer 2 RYs (deferred-CNOT masks) ----
        {
            float pre, pim;
            pre = __shfl_xor(re, 48, 64); pim = __shfl_xor(im, 48, 64);
            re = fmaf(ssl2[0], pre, cc2[0] * re); im = fmaf(ssl2[0], pim, cc2[0] * im);
            pre = __shfl_xor(re, 24, 64); pim = __shfl_xor(im, 24, 64);
            re = fmaf(ssl2[1], pre, cc2[1] * re); im = fmaf(ssl2[1], pim, cc2[1] * im);
            pre = __shfl_xor(re, 12, 64); pim = __shfl_xor(im, 12, 64);
            re = fmaf(ssl2[2], pre, cc2[2] * re); im = fmaf(ssl2[2], pim, cc2[2] * im);
            pre = __shfl_xor(re, 6, 64);  pim = __shfl_xor(im, 6, 64);
            re = fmaf(ssl2[3], pre, cc2[3] * re); im = fmaf(ssl2[3], pim, cc2[3] * im);
            pre = xor3f(re);              pim = xor3f(im);
            re = fmaf(ssl2[4], pre, cc2[4] * re); im = fmaf(ssl2[4], pim, cc2[4] * im);
            pre = __shfl_xor(re, 49, 64); pim = __shfl_xor(im, 49, 64);
            re = fmaf(ssl2[5], pre, cc2[5] * re); im = fmaf(ssl2[5], pim, cc2[5] * im);
        }
        // ---- layer 3 RYs ----
        {
            float pre, pim;
            pre = __shfl_xor(re, 40, 64); pim = __shfl_xor(im, 40, 64);
            re = fmaf(ssl3[0], pre, cc3[0] * re); im = fmaf(ssl3[0], pim, cc3[0] * im);
            pre = __shfl_xor(re, 20, 64); pim = __shfl_xor(im, 20, 64);
            re = fmaf(ssl3[1], pre, cc3[1] * re); im = fmaf(ssl3[1], pim, cc3[1] * im);
            pre = __shfl_xor(re, 10, 64); pim = __shfl_xor(im, 10, 64);
            re = fmaf(ssl3[2], pre, cc3[2] * re); im = fmaf(ssl3[2], pim, cc3[2] * im);
            pre = __shfl_xor(re, 5, 64);  pim = __shfl_xor(im, 5, 64);
            re = fmaf(ssl3[3], pre, cc3[3] * re); im = fmaf(ssl3[3], pim, cc3[3] * im);
            pre = __shfl_xor(re, 50, 64); pim = __shfl_xor(im, 50, 64);
            re = fmaf(ssl3[4], pre, cc3[4] * re); im = fmaf(ssl3[4], pim, cc3[4] * im);
            pre = __shfl_xor(re, 25, 64); pim = __shfl_xor(im, 25, 64);
            re = fmaf(ssl3[5], pre, cc3[5] * re); im = fmaf(ssl3[5], pim, cc3[5] * im);
        }

        // ---- probs -> WH butterfly -> <Z_q> at remapped lanes ----
        float p = fmaf(re, re, im * im);
        { float pp = xor1f(p);               p = pp - xsign(p, nm[5]); }
        { float pp = xor2f(p);               p = pp - xsign(p, nm[4]); }
        { float pp = __shfl_xor(p, 4, 64);   p = pp - xsign(p, nm[3]); }
        { float pp = xor8f(p);               p = pp - xsign(p, nm[2]); }
        { float pp = __shfl_xor(p, 16, 64);  p = pp - xsign(p, nm[1]); }
        { float pp = __shfl_xor(p, 32, 64);  p = pp - xsign(p, nm[0]); }

        float upd = bqr;
        upd = fmaf(rdlane(p, 44), wqr[0], upd);
        upd = fmaf(rdlane(p, 26), wqr[1], upd);
        upd = fmaf(rdlane(p, 13), wqr[2], upd);
        upd = fmaf(rdlane(p, 38), wqr[3], upd);
        upd = fmaf(rdlane(p, 51), wqr[4], upd);
        upd = fmaf(rdlane(p, 25), wqr[5], upd);
        hh = h + upd;
        xpre = xnext;
    }

    float contrib = (lane < 32) ? hh * wor : 0.0f;
    #pragma unroll
    for (int off = 32; off >= 1; off >>= 1)
        contrib += __shfl_xor(contrib, off, 64);
    if (lane == 0) out[b] = fast_sig(contrib + bo[0]);
}

extern "C" void kernel_launch(void* const* d_in, const int* in_sizes, int n_in,
                              void* d_out, int out_size, void* d_ws, size_t ws_size,
                              hipStream_t stream)
{
    const float* x    = (const float*)d_in[0];
    const float* cw1  = (const float*)d_in[1];
    const float* cb1  = (const float*)d_in[2];
    const float* cw2  = (const float*)d_in[3];
    const float* cb2  = (const float*)d_in[4];
    const float* cw3  = (const float*)d_in[5];
    const float* cb3  = (const float*)d_in[6];
    const float* W_ih = (const float*)d_in[7];
    const float* W_hh = (const float*)d_in[8];
    const float* b_ih = (const float*)d_in[9];
    const float* b_hh = (const float*)d_in[10];
    const float* qw   = (const float*)d_in[11];
    const float* Wq   = (const float*)d_in[12];
    const float* bq   = (const float*)d_in[13];
    const float* Wo   = (const float*)d_in[14];
    const float* bo   = (const float*)d_in[15];

    float* tcn = (float*)d_ws;  // [4096][256][32] f32 = 128 MiB scratch

    hipLaunchKernelGGL(tcn_kernel, dim3(B_TOT), dim3(256), 0, stream,
                       x, cw1, cb1, cw2, cb2, cw3, cb3, tcn);
    hipLaunchKernelGGL(scan_kernel, dim3(B_TOT), dim3(64), 0, stream,
                       tcn, W_ih, W_hh, b_ih, b_hh, qw, Wq, bq, Wo, bo,
                       (float*)d_out);
}

// Round 7
// 998.155 us; speedup vs baseline: 1.1759x; 1.1759x over previous
//
#include <hip/hip_runtime.h>

#define B_TOT 4096
#define T_LEN 256
#define NCH   32

typedef float f2 __attribute__((ext_vector_type(2)));
typedef float f4 __attribute__((ext_vector_type(4)));

__device__ __forceinline__ float rdlane(float v, int l) {
    return __int_as_float(__builtin_amdgcn_readlane(__float_as_int(v), l));
}
__device__ __forceinline__ float xor1f(float x) {
    return __int_as_float(__builtin_amdgcn_mov_dpp(__float_as_int(x), 0xB1, 0xF, 0xF, true));
}
__device__ __forceinline__ float xor2f(float x) {
    return __int_as_float(__builtin_amdgcn_mov_dpp(__float_as_int(x), 0x4E, 0xF, 0xF, true));
}
__device__ __forceinline__ float xor3f(float x) {
    return __int_as_float(__builtin_amdgcn_mov_dpp(__float_as_int(x), 0x1B, 0xF, 0xF, true));
}
__device__ __forceinline__ float xor8f(float x) {
    return __int_as_float(__builtin_amdgcn_mov_dpp(__float_as_int(x), 0x128, 0xF, 0xF, true));
}
__device__ __forceinline__ float xsign(float x, unsigned m) {
    return __int_as_float(__float_as_int(x) ^ (int)m);
}
__device__ __forceinline__ float fast_sig(float x) {
    return __builtin_amdgcn_rcpf(1.0f + __expf(-x));
}
__device__ __forceinline__ float fast_tanh(float x) {
    return fmaf(-2.0f, __builtin_amdgcn_rcpf(__expf(2.0f * x) + 1.0f), 1.0f);
}

// full-range sincos (one-time setup for qw which spans [0, 2pi])
__device__ __forceinline__ void fast_sincos(float x, float& s, float& c) {
    float k = rintf(x * 0.3183098861837907f);
    float r = fmaf(-k, 3.14159274101257324f, x);
    r = fmaf(-k, -8.74227765734758577e-8f, r);
    float r2 = r * r;
    float sp = fmaf(-2.50521084e-8f, r2, 2.75573192e-6f);
    sp = fmaf(sp, r2, -1.98412698e-4f);
    sp = fmaf(sp, r2, 8.33333333e-3f);
    sp = fmaf(sp, r2, -1.66666667e-1f);
    float sv = fmaf(sp * r2, r, r);
    float cp = fmaf(2.08767570e-9f, r2, -2.75573192e-7f);
    cp = fmaf(cp, r2, 2.48015873e-5f);
    cp = fmaf(cp, r2, -1.38888889e-3f);
    cp = fmaf(cp, r2, 4.16666667e-2f);
    cp = fmaf(cp, r2, -0.5f);
    float cv = fmaf(cp, r2, 1.0f);
    float sgn = ((int)k & 1) ? -1.0f : 1.0f;
    s = sv * sgn;
    c = cv * sgn;
}

// per-step sincos: input is 0.5*h with h in [-0.4, 2] -> |x| <= 1.0, so the
// pi-reduction is a bit-exact no-op (k==0); polynomial only.
__device__ __forceinline__ void sincos_poly(float x, float& s, float& c) {
    float r2 = x * x;
    float sp = fmaf(-2.50521084e-8f, r2, 2.75573192e-6f);
    sp = fmaf(sp, r2, -1.98412698e-4f);
    sp = fmaf(sp, r2, 8.33333333e-3f);
    sp = fmaf(sp, r2, -1.66666667e-1f);
    s = fmaf(sp * r2, x, x);
    float cp = fmaf(2.08767570e-9f, r2, -2.75573192e-7f);
    cp = fmaf(cp, r2, 2.48015873e-5f);
    cp = fmaf(cp, r2, -1.38888889e-3f);
    cp = fmaf(cp, r2, 4.16666667e-2f);
    cp = fmaf(cp, r2, -0.5f);
    c = fmaf(cp, r2, 1.0f);
}

// ---------------- TCN: 3x (conv1d k=3 'same' + bias + ReLU) ----------------
// pk_fma pairs (outputs 2j,2j+1), b64 LDS loads; stride 258 keeps 8B align.
__global__ __launch_bounds__(256) void tcn_kernel(
    const float* __restrict__ x,
    const float* __restrict__ cw1, const float* __restrict__ cb1,
    const float* __restrict__ cw2, const float* __restrict__ cb2,
    const float* __restrict__ cw3, const float* __restrict__ cb3,
    float* __restrict__ out)
{
    __shared__ float bufA[NCH * 258];
    __shared__ float bufB[NCH * 258];
    __shared__ float sW[NCH * 97];
    __shared__ float sB[NCH];

    const int b   = blockIdx.x;
    const int tid = threadIdx.x;
    const float* xb = x + (size_t)b * T_LEN * NCH;

    #pragma unroll
    for (int c = 0; c < 32; ++c) {
        int idx = c * 256 + tid;
        int t = idx >> 5, f = idx & 31;
        bufA[f * 258 + t] = xb[idx];
    }
    __syncthreads();

    float* bin  = bufA;
    float* bout = bufB;
    const int o  = tid & 31;
    const int t0 = (tid >> 5) * 32;

    for (int layer = 0; layer < 3; ++layer) {
        const float* Wg = (layer == 0) ? cw1 : ((layer == 1) ? cw2 : cw3);
        const float* Bg = (layer == 0) ? cb1 : ((layer == 1) ? cb2 : cb3);
        for (int idx = tid; idx < 32 * 96; idx += 256) {
            int oo = idx / 96, rem = idx - oo * 96;
            sW[oo * 97 + rem] = Wg[idx];
        }
        if (tid < 32) sB[tid] = Bg[tid];
        __syncthreads();

        f2 acc2[16];
        const float bias = sB[o];
        #pragma unroll
        for (int j = 0; j < 16; ++j) acc2[j] = f2{bias, bias};

        for (int i = 0; i < 32; ++i) {
            const float w0 = sW[o * 97 + i * 3 + 0];
            const float w1 = sW[o * 97 + i * 3 + 1];
            const float w2 = sW[o * 97 + i * 3 + 2];
            const float* row = bin + i * 258;
            const f2* rp = (const f2*)(row + t0);
            float vmE = (t0 == 0)   ? 0.0f : row[t0 - 1];
            float vpE = (t0 == 224) ? 0.0f : row[t0 + 32];
            f2 Lprev = f2{0.0f, 0.0f};
            f2 Lcur  = rp[0];
            #pragma unroll
            for (int j = 0; j < 16; ++j) {
                f2 Lnext = (j < 15) ? rp[j + 1] : f2{vpE, 0.0f};
                f2 vm = (j == 0) ? f2{vmE, Lcur.x}
                                 : __builtin_shufflevector(Lprev, Lcur, 1, 2);
                f2 vp = __builtin_shufflevector(Lcur, Lnext, 1, 2);
                acc2[j] = __builtin_elementwise_fma(f2{w0, w0}, vm,   acc2[j]);
                acc2[j] = __builtin_elementwise_fma(f2{w1, w1}, Lcur, acc2[j]);
                acc2[j] = __builtin_elementwise_fma(f2{w2, w2}, vp,   acc2[j]);
                Lprev = Lcur; Lcur = Lnext;
            }
        }
        f2* wout = (f2*)(bout + o * 258 + t0);
        #pragma unroll
        for (int j = 0; j < 16; ++j) {
            f2 r;
            r.x = fmaxf(acc2[j].x, 0.0f);
            r.y = fmaxf(acc2[j].y, 0.0f);
            wout[j] = r;
        }
        __syncthreads();
        float* tmp = bin; bin = bout; bout = tmp;
    }

    float* og = out + (size_t)b * T_LEN * NCH;
    #pragma unroll
    for (int c = 0; c < 32; ++c) {
        int idx = c * 256 + tid;
        int t = idx >> 5, f = idx & 31;
        og[idx] = bin[f * 258 + t];
    }
}

// ---------------- recurrent scan: TWO batch rows per 64-thread block -------
// Weights (row-invariant) in 128 unified regs, shared by both rows. Both
// rows' chains fully interleaved for ILP at 2 waves/SIMD. Circuit algebra
// (deferred-CNOT masks, layer-1 fold, WH readout lanes) verbatim from r5/r6.
__global__ __launch_bounds__(64, 2) void scan_kernel(
    const float* __restrict__ tcn,
    const float* __restrict__ W_ih, const float* __restrict__ W_hh,
    const float* __restrict__ b_ih, const float* __restrict__ b_hh,
    const float* __restrict__ qw,
    const float* __restrict__ Wq, const float* __restrict__ bq,
    const float* __restrict__ Wo, const float* __restrict__ bo,
    float* __restrict__ out)
{
    __shared__ __align__(16) float xcA[64], xcB[64];
    __shared__ __align__(16) float colA[24], colB[24];

    const int lane = threadIdx.x;
    const int b2   = blockIdx.x * 2;
    const float* xrowA = tcn + (size_t)b2 * T_LEN * NCH;
    const float* xrowB = xrowA + T_LEN * NCH;

    // weights: rows lane & lane+64, f2-packed (shared across both batch rows)
    f2 wih[32], whh[32];
    #pragma unroll
    for (int k = 0; k < 32; ++k) {
        wih[k] = f2{ W_ih[lane * 32 + k], W_ih[(lane + 64) * 32 + k] };
        whh[k] = f2{ W_hh[lane * 32 + k], W_hh[(lane + 64) * 32 + k] };
    }
    const f2 bias01 = f2{ b_ih[lane] + b_hh[lane],
                          b_ih[lane + 64] + b_hh[lane + 64] };

    // variational trig (uniform scalars, one-time)
    float ssu[18], ccu[18];
    {
        float s0, c0;
        int j = (lane < 18) ? lane : 0;
        fast_sincos(0.5f * qw[j], s0, c0);
        #pragma unroll
        for (int i = 0; i < 18; ++i) { ssu[i] = rdlane(s0, i); ccu[i] = rdlane(c0, i); }
    }
    float vs1 = ssu[0], vc1 = ccu[0];
    #pragma unroll
    for (int i = 1; i < 6; ++i) {
        vs1 = (lane == i) ? ssu[i] : vs1;
        vc1 = (lane == i) ? ccu[i] : vc1;
    }
    const int MU2[6] = {31, 48, 56, 60, 62, 63};
    const int MU3[6] = {53, 47, 23, 43, 21, 42};
    float ssl2[6], ssl3[6], cc2[6], cc3[6];
    #pragma unroll
    for (int q = 0; q < 6; ++q) {
        ssl2[q] = (__popc(lane & MU2[q]) & 1) ? ssu[6 + q]  : -ssu[6 + q];
        ssl3[q] = (__popc(lane & MU3[q]) & 1) ? ssu[12 + q] : -ssu[12 + q];
        cc2[q] = ccu[6 + q];
        cc3[q] = ccu[12 + q];
    }
    unsigned nm[6];
    #pragma unroll
    for (int q = 0; q < 6; ++q) nm[q] = (lane & (32 >> q)) ? 0u : 0x80000000u;
    int cidx[6];
    #pragma unroll
    for (int i = 0; i < 6; ++i) cidx[i] = i * 2 + ((lane & (32 >> i)) ? 1 : 0);
    const int r1 = (lane + 1) % 6, r2 = (lane + 2) % 6;

    float wqr[6] = {0, 0, 0, 0, 0, 0};
    float bqr = 0.0f, wor = 0.0f;
    if (lane < 32) {
        #pragma unroll
        for (int k = 0; k < 6; ++k) wqr[k] = Wq[lane * 6 + k];
        bqr = bq[lane];
        wor = Wo[lane];
    }

    float hhA = 0.0f, cellA = 0.0f, hhB = 0.0f, cellB = 0.0f;
    float xpA = (lane < 32) ? xrowA[lane] : 0.0f;
    float xpB = (lane < 32) ? xrowB[lane] : 0.0f;

    const f4* xqA = (const f4*)xcA;
    const f4* xqB = (const f4*)xcB;
    const f2* clA = (const f2*)colA;
    const f2* clB = (const f2*)colB;

    for (int t = 0; t < T_LEN; ++t) {
        if (lane < 32) {
            ((f2*)xcA)[lane] = f2{xpA, hhA};
            ((f2*)xcB)[lane] = f2{xpB, hhB};
        }
        float xnA = (lane < 32 && t < T_LEN - 1) ? xrowA[(t + 1) * 32 + lane] : 0.0f;
        float xnB = (lane < 32 && t < T_LEN - 1) ? xrowB[(t + 1) * 32 + lane] : 0.0f;

        // ---- gate matvecs, both rows interleaved ----
        f2 aA = bias01, bA_ = f2{0.0f, 0.0f};
        f2 aB = bias01, bB_ = f2{0.0f, 0.0f};
        #pragma unroll
        for (int j = 0; j < 16; ++j) {
            f4 vA = xqA[j], vB = xqB[j];
            aA  = __builtin_elementwise_fma(wih[2*j],   __builtin_shufflevector(vA, vA, 0, 0), aA);
            aB  = __builtin_elementwise_fma(wih[2*j],   __builtin_shufflevector(vB, vB, 0, 0), aB);
            aA  = __builtin_elementwise_fma(whh[2*j],   __builtin_shufflevector(vA, vA, 1, 1), aA);
            aB  = __builtin_elementwise_fma(whh[2*j],   __builtin_shufflevector(vB, vB, 1, 1), aB);
            bA_ = __builtin_elementwise_fma(wih[2*j+1], __builtin_shufflevector(vA, vA, 2, 2), bA_);
            bB_ = __builtin_elementwise_fma(wih[2*j+1], __builtin_shufflevector(vB, vB, 2, 2), bB_);
            bA_ = __builtin_elementwise_fma(whh[2*j+1], __builtin_shufflevector(vA, vA, 3, 3), bA_);
            bB_ = __builtin_elementwise_fma(whh[2*j+1], __builtin_shufflevector(vB, vB, 3, 3), bB_);
        }
        aA += bA_; aB += bB_;
        float acc0A = aA.x, acc1A = aA.y;
        float acc0B = aB.x, acc1B = aB.y;

        // ---- LSTM + chaotic maps ----
        float fgA = __shfl_xor(acc0A, 32, 64), ogA = __shfl_xor(acc1A, 32, 64);
        float fgB = __shfl_xor(acc0B, 32, 64), ogB = __shfl_xor(acc1B, 32, 64);
        float cA = fast_sig(fgA) * cellA + fast_sig(acc0A) * fast_tanh(acc1A);
        float cB = fast_sig(fgB) * cellB + fast_sig(acc0B) * fast_tanh(acc1B);
        float hA = fast_sig(ogA) * fast_tanh(cA);
        float hB = fast_sig(ogB) * fast_tanh(cB);
        hA = 3.99f * hA * (1.0f - hA);
        hB = 3.99f * hB * (1.0f - hB);
        float h0A = rdlane(hA, 0), h1A = rdlane(hA, 1);
        float h0B = rdlane(hB, 0), h1B = rdlane(hB, 1);
        float henA0 = fmaf(-1.4f * h0A, h0A, 1.0f) + h1A;
        float henB0 = fmaf(-1.4f * h0B, h0B, 1.0f) + h1B;
        hA = (lane == 0) ? henA0 : hA;
        hB = (lane == 0) ? henB0 : hB;
        hA = (lane == 1) ? 0.3f * h0A : hA;
        hB = (lane == 1) ? 0.3f * h0B : hB;
        cellA = cA; cellB = cB;

        // ---- encoding columns (fused RZ*RY*RX |0>, + layer-1 RY fold) ----
        float sOA, cOA, sOB, cOB;
        sincos_poly(0.5f * hA, sOA, cOA);
        sincos_poly(0.5f * hB, sOB, cOB);
        float s1A = __shfl(sOA, r1, 64), c1A = __shfl(cOA, r1, 64);
        float s1B = __shfl(sOB, r1, 64), c1B = __shfl(cOB, r1, 64);
        float s2A = __shfl(sOA, r2, 64), c2A = __shfl(cOA, r2, 64);
        float s2B = __shfl(sOB, r2, 64), c2B = __shfl(cOB, r2, 64);
        {
            float A_ = c1A * cOA, Bv = s1A * sOA;
            float C_ = s1A * cOA, D_ = c1A * sOA;
            float ur = fmaf(Bv, s2A,  A_ * c2A);
            float ui = fmaf(Bv, c2A, -(A_ * s2A));
            float pr = fmaf(D_, s2A,  C_ * c2A);
            float pi = fmaf(C_, s2A, -(D_ * c2A));
            float nur = fmaf(vc1, ur, -(vs1 * pr));
            float nui = fmaf(vc1, ui, -(vs1 * pi));
            float npr = fmaf(vs1, ur,  vc1 * pr);
            float npi = fmaf(vs1, ui,  vc1 * pi);
            if (lane < 6) *(f4*)&colA[lane * 4] = f4{nur, nui, npr, npi};
        }
        {
            float A_ = c1B * cOB, Bv = s1B * sOB;
            float C_ = s1B * cOB, D_ = c1B * sOB;
            float ur = fmaf(Bv, s2B,  A_ * c2B);
            float ui = fmaf(Bv, c2B, -(A_ * s2B));
            float pr = fmaf(D_, s2B,  C_ * c2B);
            float pi = fmaf(C_, s2B, -(D_ * c2B));
            float nur = fmaf(vc1, ur, -(vs1 * pr));
            float nui = fmaf(vc1, ui, -(vs1 * pi));
            float npr = fmaf(vs1, ur,  vc1 * pr);
            float npi = fmaf(vs1, ui,  vc1 * pi);
            if (lane < 6) *(f4*)&colB[lane * 4] = f4{nur, nui, npr, npi};
        }

        // ---- product states ----
        f2 gA0 = clA[cidx[0]], gB0 = clB[cidx[0]];
        float reA = gA0.x, imA = gA0.y;
        float reB = gB0.x, imB = gB0.y;
        #pragma unroll
        for (int i = 1; i < 6; ++i) {
            f2 gA = clA[cidx[i]], gB = clB[cidx[i]];
            float nrA = fmaf(reA, gA.x, -(imA * gA.y));
            float niA = fmaf(reA, gA.y,   imA * gA.x);
            float nrB = fmaf(reB, gB.x, -(imB * gB.y));
            float niB = fmaf(reB, gB.y,   imB * gB.x);
            reA = nrA; imA = niA; reB = nrB; imB = niB;
        }

        // ---- layer 2 RYs (deferred-CNOT masks), interleaved ----
        {
            float pA, qA, pB, qB;
            pA = __shfl_xor(reA, 48, 64); qA = __shfl_xor(imA, 48, 64);
            pB = __shfl_xor(reB, 48, 64); qB = __shfl_xor(imB, 48, 64);
            reA = fmaf(ssl2[0], pA, cc2[0] * reA); imA = fmaf(ssl2[0], qA, cc2[0] * imA);
            reB = fmaf(ssl2[0], pB, cc2[0] * reB); imB = fmaf(ssl2[0], qB, cc2[0] * imB);
            pA = __shfl_xor(reA, 24, 64); qA = __shfl_xor(imA, 24, 64);
            pB = __shfl_xor(reB, 24, 64); qB = __shfl_xor(imB, 24, 64);
            reA = fmaf(ssl2[1], pA, cc2[1] * reA); imA = fmaf(ssl2[1], qA, cc2[1] * imA);
            reB = fmaf(ssl2[1], pB, cc2[1] * reB); imB = fmaf(ssl2[1], qB, cc2[1] * imB);
            pA = __shfl_xor(reA, 12, 64); qA = __shfl_xor(imA, 12, 64);
            pB = __shfl_xor(reB, 12, 64); qB = __shfl_xor(imB, 12, 64);
            reA = fmaf(ssl2[2], pA, cc2[2] * reA); imA = fmaf(ssl2[2], qA, cc2[2] * imA);
            reB = fmaf(ssl2[2], pB, cc2[2] * reB); imB = fmaf(ssl2[2], qB, cc2[2] * imB);
            pA = __shfl_xor(reA, 6, 64);  qA = __shfl_xor(imA, 6, 64);
            pB = __shfl_xor(reB, 6, 64);  qB = __shfl_xor(imB, 6, 64);
            reA = fmaf(ssl2[3], pA, cc2[3] * reA); imA = fmaf(ssl2[3], qA, cc2[3] * imA);
            reB = fmaf(ssl2[3], pB, cc2[3] * reB); imB = fmaf(ssl2[3], qB, cc2[3] * imB);
            pA = xor3f(reA); qA = xor3f(imA);
            pB = xor3f(reB); qB = xor3f(imB);
            reA = fmaf(ssl2[4], pA, cc2[4] * reA); imA = fmaf(ssl2[4], qA, cc2[4] * imA);
            reB = fmaf(ssl2[4], pB, cc2[4] * reB); imB = fmaf(ssl2[4], qB, cc2[4] * imB);
            pA = __shfl_xor(reA, 49, 64); qA = __shfl_xor(imA, 49, 64);
            pB = __shfl_xor(reB, 49, 64); qB = __shfl_xor(imB, 49, 64);
            reA = fmaf(ssl2[5], pA, cc2[5] * reA); imA = fmaf(ssl2[5], qA, cc2[5] * imA);
            reB = fmaf(ssl2[5], pB, cc2[5] * reB); imB = fmaf(ssl2[5], qB, cc2[5] * imB);
        }
        // ---- layer 3 RYs ----
        {
            float pA, qA, pB, qB;
            pA = __shfl_xor(reA, 40, 64); qA = __shfl_xor(imA, 40, 64);
            pB = __shfl_xor(reB, 40, 64); qB = __shfl_xor(imB, 40, 64);
            reA = fmaf(ssl3[0], pA, cc3[0] * reA); imA = fmaf(ssl3[0], qA, cc3[0] * imA);
            reB = fmaf(ssl3[0], pB, cc3[0] * reB); imB = fmaf(ssl3[0], qB, cc3[0] * imB);
            pA = __shfl_xor(reA, 20, 64); qA = __shfl_xor(imA, 20, 64);
            pB = __shfl_xor(reB, 20, 64); qB = __shfl_xor(imB, 20, 64);
            reA = fmaf(ssl3[1], pA, cc3[1] * reA); imA = fmaf(ssl3[1], qA, cc3[1] * imA);
            reB = fmaf(ssl3[1], pB, cc3[1] * reB); imB = fmaf(ssl3[1], qB, cc3[1] * imB);
            pA = __shfl_xor(reA, 10, 64); qA = __shfl_xor(imA, 10, 64);
            pB = __shfl_xor(reB, 10, 64); qB = __shfl_xor(imB, 10, 64);
            reA = fmaf(ssl3[2], pA, cc3[2] * reA); imA = fmaf(ssl3[2], qA, cc3[2] * imA);
            reB = fmaf(ssl3[2], pB, cc3[2] * reB); imB = fmaf(ssl3[2], qB, cc3[2] * imB);
            pA = __shfl_xor(reA, 5, 64);  qA = __shfl_xor(imA, 5, 64);
            pB = __shfl_xor(reB, 5, 64);  qB = __shfl_xor(imB, 5, 64);
            reA = fmaf(ssl3[3], pA, cc3[3] * reA); imA = fmaf(ssl3[3], qA, cc3[3] * imA);
            reB = fmaf(ssl3[3], pB, cc3[3] * reB); imB = fmaf(ssl3[3], qB, cc3[3] * imB);
            pA = __shfl_xor(reA, 50, 64); qA = __shfl_xor(imA, 50, 64);
            pB = __shfl_xor(reB, 50, 64); qB = __shfl_xor(imB, 50, 64);
            reA = fmaf(ssl3[4], pA, cc3[4] * reA); imA = fmaf(ssl3[4], qA, cc3[4] * imA);
            reB = fmaf(ssl3[4], pB, cc3[4] * reB); imB = fmaf(ssl3[4], qB, cc3[4] * imB);
            pA = __shfl_xor(reA, 25, 64); qA = __shfl_xor(imA, 25, 64);
            pB = __shfl_xor(reB, 25, 64); qB = __shfl_xor(imB, 25, 64);
            reA = fmaf(ssl3[5], pA, cc3[5] * reA); imA = fmaf(ssl3[5], qA, cc3[5] * imA);
            reB = fmaf(ssl3[5], pB, cc3[5] * reB); imB = fmaf(ssl3[5], qB, cc3[5] * imB);
        }

        // ---- probs -> WH butterfly -> <Z_q> ----
        float pA = fmaf(reA, reA, imA * imA);
        float pB = fmaf(reB, reB, imB * imB);
        { float tA = xor1f(pA), tB = xor1f(pB);
          pA = tA - xsign(pA, nm[5]); pB = tB - xsign(pB, nm[5]); }
        { float tA = xor2f(pA), tB = xor2f(pB);
          pA = tA - xsign(pA, nm[4]); pB = tB - xsign(pB, nm[4]); }
        { float tA = __shfl_xor(pA, 4, 64), tB = __shfl_xor(pB, 4, 64);
          pA = tA - xsign(pA, nm[3]); pB = tB - xsign(pB, nm[3]); }
        { float tA = xor8f(pA), tB = xor8f(pB);
          pA = tA - xsign(pA, nm[2]); pB = tB - xsign(pB, nm[2]); }
        { float tA = __shfl_xor(pA, 16, 64), tB = __shfl_xor(pB, 16, 64);
          pA = tA - xsign(pA, nm[1]); pB = tB - xsign(pB, nm[1]); }
        { float tA = __shfl_xor(pA, 32, 64), tB = __shfl_xor(pB, 32, 64);
          pA = tA - xsign(pA, nm[0]); pB = tB - xsign(pB, nm[0]); }

        float updA = bqr, updB = bqr;
        updA = fmaf(rdlane(pA, 44), wqr[0], updA); updB = fmaf(rdlane(pB, 44), wqr[0], updB);
        updA = fmaf(rdlane(pA, 26), wqr[1], updA); updB = fmaf(rdlane(pB, 26), wqr[1], updB);
        updA = fmaf(rdlane(pA, 13), wqr[2], updA); updB = fmaf(rdlane(pB, 13), wqr[2], updB);
        updA = fmaf(rdlane(pA, 38), wqr[3], updA); updB = fmaf(rdlane(pB, 38), wqr[3], updB);
        updA = fmaf(rdlane(pA, 51), wqr[4], updA); updB = fmaf(rdlane(pB, 51), wqr[4], updB);
        updA = fmaf(rdlane(pA, 25), wqr[5], updA); updB = fmaf(rdlane(pB, 25), wqr[5], updB);
        hhA = hA + updA;
        hhB = hB + updB;
        xpA = xnA; xpB = xnB;
    }

    float cA = (lane < 32) ? hhA * wor : 0.0f;
    float cB = (lane < 32) ? hhB * wor : 0.0f;
    #pragma unroll
    for (int off = 32; off >= 1; off >>= 1) {
        cA += __shfl_xor(cA, off, 64);
        cB += __shfl_xor(cB, off, 64);
    }
    if (lane == 0) {
        float bo0 = bo[0];
        out[b2]     = fast_sig(cA + bo0);
        out[b2 + 1] = fast_sig(cB + bo0);
    }
}

extern "C" void kernel_launch(void* const* d_in, const int* in_sizes, int n_in,
                              void* d_out, int out_size, void* d_ws, size_t ws_size,
                              hipStream_t stream)
{
    const float* x    = (const float*)d_in[0];
    const float* cw1  = (const float*)d_in[1];
    const float* cb1  = (const float*)d_in[2];
    const float* cw2  = (const float*)d_in[3];
    const float* cb2  = (const float*)d_in[4];
    const float* cw3  = (const float*)d_in[5];
    const float* cb3  = (const float*)d_in[6];
    const float* W_ih = (const float*)d_in[7];
    const float* W_hh = (const float*)d_in[8];
    const float* b_ih = (const float*)d_in[9];
    const float* b_hh = (const float*)d_in[10];
    const float* qw   = (const float*)d_in[11];
    const float* Wq   = (const float*)d_in[12];
    const float* bq   = (const float*)d_in[13];
    const float* Wo   = (const float*)d_in[14];
    const float* bo   = (const float*)d_in[15];

    float* tcn = (float*)d_ws;  // [4096][256][32] f32 = 128 MiB scratch

    hipLaunchKernelGGL(tcn_kernel, dim3(B_TOT), dim3(256), 0, stream,
                       x, cw1, cb1, cw2, cb2, cw3, cb3, tcn);
    hipLaunchKernelGGL(scan_kernel, dim3(B_TOT / 2), dim3(64), 0, stream,
                       tcn, W_ih, W_hh, b_ih, b_hh, qw, Wq, bq, Wo, bo,
                       (float*)d_out);
}

// Round 8
// 995.653 us; speedup vs baseline: 1.1788x; 1.0025x over previous
//
#include <hip/hip_runtime.h>

#define B_TOT 4096
#define T_LEN 256
#define NCH   32

typedef float f2 __attribute__((ext_vector_type(2)));
typedef float f4 __attribute__((ext_vector_type(4)));

__device__ __forceinline__ float rdlane(float v, int l) {
    return __int_as_float(__builtin_amdgcn_readlane(__float_as_int(v), l));
}
__device__ __forceinline__ float xor1f(float x) {
    return __int_as_float(__builtin_amdgcn_mov_dpp(__float_as_int(x), 0xB1, 0xF, 0xF, true));
}
__device__ __forceinline__ float xor2f(float x) {
    return __int_as_float(__builtin_amdgcn_mov_dpp(__float_as_int(x), 0x4E, 0xF, 0xF, true));
}
__device__ __forceinline__ float xor3f(float x) {
    return __int_as_float(__builtin_amdgcn_mov_dpp(__float_as_int(x), 0x1B, 0xF, 0xF, true));
}
__device__ __forceinline__ float xor8f(float x) {
    return __int_as_float(__builtin_amdgcn_mov_dpp(__float_as_int(x), 0x128, 0xF, 0xF, true));
}
__device__ __forceinline__ float xsign(float x, unsigned m) {
    return __int_as_float(__float_as_int(x) ^ (int)m);
}
__device__ __forceinline__ float fast_sig(float x) {
    return __builtin_amdgcn_rcpf(1.0f + __expf(-x));
}
__device__ __forceinline__ float fast_tanh(float x) {
    return fmaf(-2.0f, __builtin_amdgcn_rcpf(__expf(2.0f * x) + 1.0f), 1.0f);
}

// full-range sincos (one-time setup for qw which spans [0, 2pi])
__device__ __forceinline__ void fast_sincos(float x, float& s, float& c) {
    float k = rintf(x * 0.3183098861837907f);
    float r = fmaf(-k, 3.14159274101257324f, x);
    r = fmaf(-k, -8.74227765734758577e-8f, r);
    float r2 = r * r;
    float sp = fmaf(-2.50521084e-8f, r2, 2.75573192e-6f);
    sp = fmaf(sp, r2, -1.98412698e-4f);
    sp = fmaf(sp, r2, 8.33333333e-3f);
    sp = fmaf(sp, r2, -1.66666667e-1f);
    float sv = fmaf(sp * r2, r, r);
    float cp = fmaf(2.08767570e-9f, r2, -2.75573192e-7f);
    cp = fmaf(cp, r2, 2.48015873e-5f);
    cp = fmaf(cp, r2, -1.38888889e-3f);
    cp = fmaf(cp, r2, 4.16666667e-2f);
    cp = fmaf(cp, r2, -0.5f);
    float cv = fmaf(cp, r2, 1.0f);
    float sgn = ((int)k & 1) ? -1.0f : 1.0f;
    s = sv * sgn;
    c = cv * sgn;
}

// per-step sincos: input is 0.5*h with h in [-0.4, 2] -> |x| <= 1.0, so the
// pi-reduction is a bit-exact no-op (k==0); polynomial only.
__device__ __forceinline__ void sincos_poly(float x, float& s, float& c) {
    float r2 = x * x;
    float sp = fmaf(-2.50521084e-8f, r2, 2.75573192e-6f);
    sp = fmaf(sp, r2, -1.98412698e-4f);
    sp = fmaf(sp, r2, 8.33333333e-3f);
    sp = fmaf(sp, r2, -1.66666667e-1f);
    s = fmaf(sp * r2, x, x);
    float cp = fmaf(2.08767570e-9f, r2, -2.75573192e-7f);
    cp = fmaf(cp, r2, 2.48015873e-5f);
    cp = fmaf(cp, r2, -1.38888889e-3f);
    cp = fmaf(cp, r2, 4.16666667e-2f);
    cp = fmaf(cp, r2, -0.5f);
    c = fmaf(cp, r2, 1.0f);
}

// ---------------- TCN: 3x (conv1d k=3 'same' + bias + ReLU) ----------------
// pk_fma pairs (outputs 2j,2j+1), b64 LDS loads; stride 258 keeps 8B align.
__global__ __launch_bounds__(256) void tcn_kernel(
    const float* __restrict__ x,
    const float* __restrict__ cw1, const float* __restrict__ cb1,
    const float* __restrict__ cw2, const float* __restrict__ cb2,
    const float* __restrict__ cw3, const float* __restrict__ cb3,
    float* __restrict__ out)
{
    __shared__ float bufA[NCH * 258];
    __shared__ float bufB[NCH * 258];
    __shared__ float sW[NCH * 97];
    __shared__ float sB[NCH];

    const int b   = blockIdx.x;
    const int tid = threadIdx.x;
    const float* xb = x + (size_t)b * T_LEN * NCH;

    #pragma unroll
    for (int c = 0; c < 32; ++c) {
        int idx = c * 256 + tid;
        int t = idx >> 5, f = idx & 31;
        bufA[f * 258 + t] = xb[idx];
    }
    __syncthreads();

    float* bin  = bufA;
    float* bout = bufB;
    const int o  = tid & 31;
    const int t0 = (tid >> 5) * 32;

    for (int layer = 0; layer < 3; ++layer) {
        const float* Wg = (layer == 0) ? cw1 : ((layer == 1) ? cw2 : cw3);
        const float* Bg = (layer == 0) ? cb1 : ((layer == 1) ? cb2 : cb3);
        for (int idx = tid; idx < 32 * 96; idx += 256) {
            int oo = idx / 96, rem = idx - oo * 96;
            sW[oo * 97 + rem] = Wg[idx];
        }
        if (tid < 32) sB[tid] = Bg[tid];
        __syncthreads();

        f2 acc2[16];
        const float bias = sB[o];
        #pragma unroll
        for (int j = 0; j < 16; ++j) acc2[j] = f2{bias, bias};

        for (int i = 0; i < 32; ++i) {
            const float w0 = sW[o * 97 + i * 3 + 0];
            const float w1 = sW[o * 97 + i * 3 + 1];
            const float w2 = sW[o * 97 + i * 3 + 2];
            const float* row = bin + i * 258;
            const f2* rp = (const f2*)(row + t0);
            float vmE = (t0 == 0)   ? 0.0f : row[t0 - 1];
            float vpE = (t0 == 224) ? 0.0f : row[t0 + 32];
            f2 Lprev = f2{0.0f, 0.0f};
            f2 Lcur  = rp[0];
            #pragma unroll
            for (int j = 0; j < 16; ++j) {
                f2 Lnext = (j < 15) ? rp[j + 1] : f2{vpE, 0.0f};
                f2 vm = (j == 0) ? f2{vmE, Lcur.x}
                                 : __builtin_shufflevector(Lprev, Lcur, 1, 2);
                f2 vp = __builtin_shufflevector(Lcur, Lnext, 1, 2);
                acc2[j] = __builtin_elementwise_fma(f2{w0, w0}, vm,   acc2[j]);
                acc2[j] = __builtin_elementwise_fma(f2{w1, w1}, Lcur, acc2[j]);
                acc2[j] = __builtin_elementwise_fma(f2{w2, w2}, vp,   acc2[j]);
                Lprev = Lcur; Lcur = Lnext;
            }
        }
        f2* wout = (f2*)(bout + o * 258 + t0);
        #pragma unroll
        for (int j = 0; j < 16; ++j) {
            f2 r;
            r.x = fmaxf(acc2[j].x, 0.0f);
            r.y = fmaxf(acc2[j].y, 0.0f);
            wout[j] = r;
        }
        __syncthreads();
        float* tmp = bin; bin = bout; bout = tmp;
    }

    float* og = out + (size_t)b * T_LEN * NCH;
    #pragma unroll
    for (int c = 0; c < 32; ++c) {
        int idx = c * 256 + tid;
        int t = idx >> 5, f = idx & 31;
        og[idx] = bin[f * 258 + t];
    }
}

// ---------------- recurrent scan: TWO batch rows per 64-thread block -------
// Weights (row-invariant) in 128 unified regs, shared by both rows. Both
// rows' chains fully interleaved for ILP at 2 waves/SIMD. Circuit algebra
// (deferred-CNOT masks, layer-1 fold, WH readout lanes) verbatim from r5/r6.
__global__ __launch_bounds__(64, 2) void scan_kernel(
    const float* __restrict__ tcn,
    const float* __restrict__ W_ih, const float* __restrict__ W_hh,
    const float* __restrict__ b_ih, const float* __restrict__ b_hh,
    const float* __restrict__ qw,
    const float* __restrict__ Wq, const float* __restrict__ bq,
    const float* __restrict__ Wo, const float* __restrict__ bo,
    float* __restrict__ out)
{
    __shared__ __align__(16) float xcA[64], xcB[64];
    __shared__ __align__(16) float colA[24], colB[24];

    const int lane = threadIdx.x;
    const int b2   = blockIdx.x * 2;
    const float* xrowA = tcn + (size_t)b2 * T_LEN * NCH;
    const float* xrowB = xrowA + T_LEN * NCH;

    // weights: rows lane & lane+64, f2-packed (shared across both batch rows)
    f2 wih[32], whh[32];
    #pragma unroll
    for (int k = 0; k < 32; ++k) {
        wih[k] = f2{ W_ih[lane * 32 + k], W_ih[(lane + 64) * 32 + k] };
        whh[k] = f2{ W_hh[lane * 32 + k], W_hh[(lane + 64) * 32 + k] };
    }
    const f2 bias01 = f2{ b_ih[lane] + b_hh[lane],
                          b_ih[lane + 64] + b_hh[lane + 64] };

    // variational trig (uniform scalars, one-time)
    float ssu[18], ccu[18];
    {
        float s0, c0;
        int j = (lane < 18) ? lane : 0;
        fast_sincos(0.5f * qw[j], s0, c0);
        #pragma unroll
        for (int i = 0; i < 18; ++i) { ssu[i] = rdlane(s0, i); ccu[i] = rdlane(c0, i); }
    }
    float vs1 = ssu[0], vc1 = ccu[0];
    #pragma unroll
    for (int i = 1; i < 6; ++i) {
        vs1 = (lane == i) ? ssu[i] : vs1;
        vc1 = (lane == i) ? ccu[i] : vc1;
    }
    const int MU2[6] = {31, 48, 56, 60, 62, 63};
    const int MU3[6] = {53, 47, 23, 43, 21, 42};
    float ssl2[6], ssl3[6], cc2[6], cc3[6];
    #pragma unroll
    for (int q = 0; q < 6; ++q) {
        ssl2[q] = (__popc(lane & MU2[q]) & 1) ? ssu[6 + q]  : -ssu[6 + q];
        ssl3[q] = (__popc(lane & MU3[q]) & 1) ? ssu[12 + q] : -ssu[12 + q];
        cc2[q] = ccu[6 + q];
        cc3[q] = ccu[12 + q];
    }
    unsigned nm[6];
    #pragma unroll
    for (int q = 0; q < 6; ++q) nm[q] = (lane & (32 >> q)) ? 0u : 0x80000000u;
    int cidx[6];
    #pragma unroll
    for (int i = 0; i < 6; ++i) cidx[i] = i * 2 + ((lane & (32 >> i)) ? 1 : 0);
    const int r1 = (lane + 1) % 6, r2 = (lane + 2) % 6;

    float wqr[6] = {0, 0, 0, 0, 0, 0};
    float bqr = 0.0f, wor = 0.0f;
    if (lane < 32) {
        #pragma unroll
        for (int k = 0; k < 6; ++k) wqr[k] = Wq[lane * 6 + k];
        bqr = bq[lane];
        wor = Wo[lane];
    }

    float hhA = 0.0f, cellA = 0.0f, hhB = 0.0f, cellB = 0.0f;
    float xpA = (lane < 32) ? xrowA[lane] : 0.0f;
    float xpB = (lane < 32) ? xrowB[lane] : 0.0f;

    const f4* xqA = (const f4*)xcA;
    const f4* xqB = (const f4*)xcB;
    const f2* clA = (const f2*)colA;
    const f2* clB = (const f2*)colB;

    for (int t = 0; t < T_LEN; ++t) {
        if (lane < 32) {
            ((f2*)xcA)[lane] = f2{xpA, hhA};
            ((f2*)xcB)[lane] = f2{xpB, hhB};
        }
        float xnA = (lane < 32 && t < T_LEN - 1) ? xrowA[(t + 1) * 32 + lane] : 0.0f;
        float xnB = (lane < 32 && t < T_LEN - 1) ? xrowB[(t + 1) * 32 + lane] : 0.0f;

        // ---- gate matvecs, both rows interleaved ----
        f2 aA = bias01, bA_ = f2{0.0f, 0.0f};
        f2 aB = bias01, bB_ = f2{0.0f, 0.0f};
        #pragma unroll
        for (int j = 0; j < 16; ++j) {
            f4 vA = xqA[j], vB = xqB[j];
            aA  = __builtin_elementwise_fma(wih[2*j],   __builtin_shufflevector(vA, vA, 0, 0), aA);
            aB  = __builtin_elementwise_fma(wih[2*j],   __builtin_shufflevector(vB, vB, 0, 0), aB);
            aA  = __builtin_elementwise_fma(whh[2*j],   __builtin_shufflevector(vA, vA, 1, 1), aA);
            aB  = __builtin_elementwise_fma(whh[2*j],   __builtin_shufflevector(vB, vB, 1, 1), aB);
            bA_ = __builtin_elementwise_fma(wih[2*j+1], __builtin_shufflevector(vA, vA, 2, 2), bA_);
            bB_ = __builtin_elementwise_fma(wih[2*j+1], __builtin_shufflevector(vB, vB, 2, 2), bB_);
            bA_ = __builtin_elementwise_fma(whh[2*j+1], __builtin_shufflevector(vA, vA, 3, 3), bA_);
            bB_ = __builtin_elementwise_fma(whh[2*j+1], __builtin_shufflevector(vB, vB, 3, 3), bB_);
        }
        aA += bA_; aB += bB_;
        float acc0A = aA.x, acc1A = aA.y;
        float acc0B = aB.x, acc1B = aB.y;

        // ---- LSTM + chaotic maps ----
        float fgA = __shfl_xor(acc0A, 32, 64), ogA = __shfl_xor(acc1A, 32, 64);
        float fgB = __shfl_xor(acc0B, 32, 64), ogB = __shfl_xor(acc1B, 32, 64);
        float cA = fast_sig(fgA) * cellA + fast_sig(acc0A) * fast_tanh(acc1A);
        float cB = fast_sig(fgB) * cellB + fast_sig(acc0B) * fast_tanh(acc1B);
        float hA = fast_sig(ogA) * fast_tanh(cA);
        float hB = fast_sig(ogB) * fast_tanh(cB);
        hA = 3.99f * hA * (1.0f - hA);
        hB = 3.99f * hB * (1.0f - hB);
        float h0A = rdlane(hA, 0), h1A = rdlane(hA, 1);
        float h0B = rdlane(hB, 0), h1B = rdlane(hB, 1);
        float henA0 = fmaf(-1.4f * h0A, h0A, 1.0f) + h1A;
        float henB0 = fmaf(-1.4f * h0B, h0B, 1.0f) + h1B;
        hA = (lane == 0) ? henA0 : hA;
        hB = (lane == 0) ? henB0 : hB;
        hA = (lane == 1) ? 0.3f * h0A : hA;
        hB = (lane == 1) ? 0.3f * h0B : hB;
        cellA = cA; cellB = cB;

        // ---- encoding columns (fused RZ*RY*RX |0>, + layer-1 RY fold) ----
        float sOA, cOA, sOB, cOB;
        sincos_poly(0.5f * hA, sOA, cOA);
        sincos_poly(0.5f * hB, sOB, cOB);
        float s1A = __shfl(sOA, r1, 64), c1A = __shfl(cOA, r1, 64);
        float s1B = __shfl(sOB, r1, 64), c1B = __shfl(cOB, r1, 64);
        float s2A = __shfl(sOA, r2, 64), c2A = __shfl(cOA, r2, 64);
        float s2B = __shfl(sOB, r2, 64), c2B = __shfl(cOB, r2, 64);
        {
            float A_ = c1A * cOA, Bv = s1A * sOA;
            float C_ = s1A * cOA, D_ = c1A * sOA;
            float ur = fmaf(Bv, s2A,  A_ * c2A);
            float ui = fmaf(Bv, c2A, -(A_ * s2A));
            float pr = fmaf(D_, s2A,  C_ * c2A);
            float pi = fmaf(C_, s2A, -(D_ * c2A));
            float nur = fmaf(vc1, ur, -(vs1 * pr));
            float nui = fmaf(vc1, ui, -(vs1 * pi));
            float npr = fmaf(vs1, ur,  vc1 * pr);
            float npi = fmaf(vs1, ui,  vc1 * pi);
            if (lane < 6) *(f4*)&colA[lane * 4] = f4{nur, nui, npr, npi};
        }
        {
            float A_ = c1B * cOB, Bv = s1B * sOB;
            float C_ = s1B * cOB, D_ = c1B * sOB;
            float ur = fmaf(Bv, s2B,  A_ * c2B);
            float ui = fmaf(Bv, c2B, -(A_ * s2B));
            float pr = fmaf(D_, s2B,  C_ * c2B);
            float pi = fmaf(C_, s2B, -(D_ * c2B));
            float nur = fmaf(vc1, ur, -(vs1 * pr));
            float nui = fmaf(vc1, ui, -(vs1 * pi));
            float npr = fmaf(vs1, ur,  vc1 * pr);
            float npi = fmaf(vs1, ui,  vc1 * pi);
            if (lane < 6) *(f4*)&colB[lane * 4] = f4{nur, nui, npr, npi};
        }

        // ---- product states ----
        f2 gA0 = clA[cidx[0]], gB0 = clB[cidx[0]];
        float reA = gA0.x, imA = gA0.y;
        float reB = gB0.x, imB = gB0.y;
        #pragma unroll
        for (int i = 1; i < 6; ++i) {
            f2 gA = clA[cidx[i]], gB = clB[cidx[i]];
            float nrA = fmaf(reA, gA.x, -(imA * gA.y));
            float niA = fmaf(reA, gA.y,   imA * gA.x);
            float nrB = fmaf(reB, gB.x, -(imB * gB.y));
            float niB = fmaf(reB, gB.y,   imB * gB.x);
            reA = nrA; imA = niA; reB = nrB; imB = niB;
        }

        // ---- layer 2 RYs (deferred-CNOT masks), interleaved ----
        {
            float pA, qA, pB, qB;
            pA = __shfl_xor(reA, 48, 64); qA = __shfl_xor(imA, 48, 64);
            pB = __shfl_xor(reB, 48, 64); qB = __shfl_xor(imB, 48, 64);
            reA = fmaf(ssl2[0], pA, cc2[0] * reA); imA = fmaf(ssl2[0], qA, cc2[0] * imA);
            reB = fmaf(ssl2[0], pB, cc2[0] * reB); imB = fmaf(ssl2[0], qB, cc2[0] * imB);
            pA = __shfl_xor(reA, 24, 64); qA = __shfl_xor(imA, 24, 64);
            pB = __shfl_xor(reB, 24, 64); qB = __shfl_xor(imB, 24, 64);
            reA = fmaf(ssl2[1], pA, cc2[1] * reA); imA = fmaf(ssl2[1], qA, cc2[1] * imA);
            reB = fmaf(ssl2[1], pB, cc2[1] * reB); imB = fmaf(ssl2[1], qB, cc2[1] * imB);
            pA = __shfl_xor(reA, 12, 64); qA = __shfl_xor(imA, 12, 64);
            pB = __shfl_xor(reB, 12, 64); qB = __shfl_xor(imB, 12, 64);
            reA = fmaf(ssl2[2], pA, cc2[2] * reA); imA = fmaf(ssl2[2], qA, cc2[2] * imA);
            reB = fmaf(ssl2[2], pB, cc2[2] * reB); imB = fmaf(ssl2[2], qB, cc2[2] * imB);
            pA = __shfl_xor(reA, 6, 64);  qA = __shfl_xor(imA, 6, 64);
            pB = __shfl_xor(reB, 6, 64);  qB = __shfl_xor(imB, 6, 64);
            reA = fmaf(ssl2[3], pA, cc2[3] * reA); imA = fmaf(ssl2[3], qA, cc2[3] * imA);
            reB = fmaf(ssl2[3], pB, cc2[3] * reB); imB = fmaf(ssl2[3], qB, cc2[3] * imB);
            pA = xor3f(reA); qA = xor3f(imA);
            pB = xor3f(reB); qB = xor3f(imB);
            reA = fmaf(ssl2[4], pA, cc2[4] * reA); imA = fmaf(ssl2[4], qA, cc2[4] * imA);
            reB = fmaf(ssl2[4], pB, cc2[4] * reB); imB = fmaf(ssl2[4], qB, cc2[4] * imB);
            pA = __shfl_xor(reA, 49, 64); qA = __shfl_xor(imA, 49, 64);
            pB = __shfl_xor(reB, 49, 64); qB = __shfl_xor(imB, 49, 64);
            reA = fmaf(ssl2[5], pA, cc2[5] * reA); imA = fmaf(ssl2[5], qA, cc2[5] * imA);
            reB = fmaf(ssl2[5], pB, cc2[5] * reB); imB = fmaf(ssl2[5], qB, cc2[5] * imB);
        }
        // ---- layer 3 RYs ----
        {
            float pA, qA, pB, qB;
            pA = __shfl_xor(reA, 40, 64); qA = __shfl_xor(imA, 40, 64);
            pB = __shfl_xor(reB, 40, 64); qB = __shfl_xor(imB, 40, 64);
            reA = fmaf(ssl3[0], pA, cc3[0] * reA); imA = fmaf(ssl3[0], qA, cc3[0] * imA);
            reB = fmaf(ssl3[0], pB, cc3[0] * reB); imB = fmaf(ssl3[0], qB, cc3[0] * imB);
            pA = __shfl_xor(reA, 20, 64); qA = __shfl_xor(imA, 20, 64);
            pB = __shfl_xor(reB, 20, 64); qB = __shfl_xor(imB, 20, 64);
            reA = fmaf(ssl3[1], pA, cc3[1] * reA); imA = fmaf(ssl3[1], qA, cc3[1] * imA);
            reB = fmaf(ssl3[1], pB, cc3[1] * reB); imB = fmaf(ssl3[1], qB, cc3[1] * imB);
            pA = __shfl_xor(reA, 10, 64); qA = __shfl_xor(imA, 10, 64);
            pB = __shfl_xor(reB, 10, 64); qB = __shfl_xor(imB, 10, 64);
            reA = fmaf(ssl3[2], pA, cc3[2] * reA); imA = fmaf(ssl3[2], qA, cc3[2] * imA);
            reB = fmaf(ssl3[2], pB, cc3[2] * reB); imB = fmaf(ssl3[2], qB, cc3[2] * imB);
            pA = __shfl_xor(reA, 5, 64);  qA = __shfl_xor(imA, 5, 64);
            pB = __shfl_xor(reB, 5, 64);  qB = __shfl_xor(imB, 5, 64);
            reA = fmaf(ssl3[3], pA, cc3[3] * reA); imA = fmaf(ssl3[3], qA, cc3[3] * imA);
            reB = fmaf(ssl3[3], pB, cc3[3] * reB); imB = fmaf(ssl3[3], qB, cc3[3] * imB);
            pA = __shfl_xor(reA, 50, 64); qA = __shfl_xor(imA, 50, 64);
            pB = __shfl_xor(reB, 50, 64); qB = __shfl_xor(imB, 50, 64);
            reA = fmaf(ssl3[4], pA, cc3[4] * reA); imA = fmaf(ssl3[4], qA, cc3[4] * imA);
            reB = fmaf(ssl3[4], pB, cc3[4] * reB); imB = fmaf(ssl3[4], qB, cc3[4] * imB);
            pA = __shfl_xor(reA, 25, 64); qA = __shfl_xor(imA, 25, 64);
            pB = __shfl_xor(reB, 25, 64); qB = __shfl_xor(imB, 25, 64);
            reA = fmaf(ssl3[5], pA, cc3[5] * reA); imA = fmaf(ssl3[5], qA, cc3[5] * imA);
            reB = fmaf(ssl3[5], pB, cc3[5] * reB); imB = fmaf(ssl3[5], qB, cc3[5] * imB);
        }

        // ---- probs -> WH butterfly -> <Z_q> ----
        float pA = fmaf(reA, reA, imA * imA);
        float pB = fmaf(reB, reB, imB * imB);
        { float tA = xor1f(pA), tB = xor1f(pB);
          pA = tA - xsign(pA, nm[5]); pB = tB - xsign(pB, nm[5]); }
        { float tA = xor2f(pA), tB = xor2f(pB);
          pA = tA - xsign(pA, nm[4]); pB = tB - xsign(pB, nm[4]); }
        { float tA = __shfl_xor(pA, 4, 64), tB = __shfl_xor(pB, 4, 64);
          pA = tA - xsign(pA, nm[3]); pB = tB - xsign(pB, nm[3]); }
        { float tA = xor8f(pA), tB = xor8f(pB);
          pA = tA - xsign(pA, nm[2]); pB = tB - xsign(pB, nm[2]); }
        { float tA = __shfl_xor(pA, 16, 64), tB = __shfl_xor(pB, 16, 64);
          pA = tA - xsign(pA, nm[1]); pB = tB - xsign(pB, nm[1]); }
        { float tA = __shfl_xor(pA, 32, 64), tB = __shfl_xor(pB, 32, 64);
          pA = tA - xsign(pA, nm[0]); pB = tB - xsign(pB, nm[0]); }

        float updA = bqr, updB = bqr;
        updA = fmaf(rdlane(pA, 44), wqr[0], updA); updB = fmaf(rdlane(pB, 44), wqr[0], updB);
        updA = fmaf(rdlane(pA, 26), wqr[1], updA); updB = fmaf(rdlane(pB, 26), wqr[1], updB);
        updA = fmaf(rdlane(pA, 13), wqr[2], updA); updB = fmaf(rdlane(pB, 13), wqr[2], updB);
        updA = fmaf(rdlane(pA, 38), wqr[3], updA); updB = fmaf(rdlane(pB, 38), wqr[3], updB);
        updA = fmaf(rdlane(pA, 51), wqr[4], updA); updB = fmaf(rdlane(pB, 51), wqr[4], updB);
        updA = fmaf(rdlane(pA, 25), wqr[5], updA); updB = fmaf(rdlane(pB, 25), wqr[5], updB);
        hhA = hA + updA;
        hhB = hB + updB;
        xpA = xnA; xpB = xnB;
    }

    float cA = (lane < 32) ? hhA * wor : 0.0f;
    float cB = (lane < 32) ? hhB * wor : 0.0f;
    #pragma unroll
    for (int off = 32; off >= 1; off >>= 1) {
        cA += __shfl_xor(cA, off, 64);
        cB += __shfl_xor(cB, off, 64);
    }
    if (lane == 0) {
        float bo0 = bo[0];
        out[b2]     = fast_sig(cA + bo0);
        out[b2 + 1] = fast_sig(cB + bo0);
    }
}

extern "C" void kernel_launch(void* const* d_in, const int* in_sizes, int n_in,
                              void* d_out, int out_size, void* d_ws, size_t ws_size,
                              hipStream_t stream)
{
    const float* x    = (const float*)d_in[0];
    const float* cw1  = (const float*)d_in[1];
    const float* cb1  = (const float*)d_in[2];
    const float* cw2  = (const float*)d_in[3];
    const float* cb2  = (const float*)d_in[4];
    const float* cw3  = (const float*)d_in[5];
    const float* cb3  = (const float*)d_in[6];
    const float* W_ih = (const float*)d_in[7];
    const float* W_hh = (const float*)d_in[8];
    const float* b_ih = (const float*)d_in[9];
    const float* b_hh = (const float*)d_in[10];
    const float* qw   = (const float*)d_in[11];
    const float* Wq   = (const float*)d_in[12];
    const float* bq   = (const float*)d_in[13];
    const float* Wo   = (const float*)d_in[14];
    const float* bo   = (const float*)d_in[15];

    float* tcn = (float*)d_ws;  // [4096][256][32] f32 = 128 MiB scratch

    hipLaunchKernelGGL(tcn_kernel, dim3(B_TOT), dim3(256), 0, stream,
                       x, cw1, cb1, cw2, cb2, cw3, cb3, tcn);
    hipLaunchKernelGGL(scan_kernel, dim3(B_TOT / 2), dim3(64), 0, stream,
                       tcn, W_ih, W_hh, b_ih, b_hh, qw, Wq, bq, Wo, bo,
                       (float*)d_out);
}